// Round 6
// baseline (225.871 us; speedup 1.0000x reference)
//
#include <hip/hip_runtime.h>
#include <hip/hip_bf16.h>

// out[b,o,n] = sum_{k,c} input[b,c,n] * weight[o,k,c] * score[b,k,n]
// B=8, C_IN=16, C_OUT=16, K=4, N=524288. fp32 in/out.
//
// MFMA formulation: out[b,:,n] = W'(16x64) . Z(64,n),  Z[k*16+c, n] = a[k,n]*x[c,n].
// One wave = one 16(o) x 16(n) tile via 2x mfma_f32_16x16x32_bf16 (K=64).
// Round-5 lesson: fp32 vector path is VALU-issue-bound (addressing+FMA ~130us of
// issue vs 58us useful). MFMA removes the 1024-FMA/n contraction from the VALU.

constexpr int B     = 8;
constexpr int C_IN  = 16;
constexpr int C_OUT = 16;
constexpr int KK    = 4;
constexpr int N     = 524288;                 // 2^19
constexpr int TILES_PER_BATCH = N / 16;       // 32768
constexpr int T_PER_WAVE = 32;                // tiles per wave
constexpr int TOTAL_WAVES = B * TILES_PER_BATCH / T_PER_WAVE;  // 8192
constexpr int WPB = 4;                        // waves per 256-thread block
constexpr int GRID = TOTAL_WAVES / WPB;       // 2048

typedef short bf16x8 __attribute__((ext_vector_type(8)));
typedef float f32x4  __attribute__((ext_vector_type(4)));

__device__ inline short f2bf(float f) {
    return __builtin_bit_cast(short, __float2bfloat16(f));
}

__global__ __launch_bounds__(256) void
TransformConv1d_39264591020709_kernel(const float* __restrict__ in,
                                      const float* __restrict__ w,
                                      const float* __restrict__ sc,
                                      float* __restrict__ out) {
    const int tid  = threadIdx.x;
    const int lane = tid & 63;
    const int wv   = blockIdx.x * WPB + (tid >> 6);
    const int g    = lane >> 4;    // lane group 0..3
    const int col  = lane & 15;    // n-offset within tile; also o-index for A frag

    const int tile0 = wv * T_PER_WAVE;
    const int b     = tile0 / TILES_PER_BATCH;            // waves never straddle batches
    const int n0    = (tile0 % TILES_PER_BATCH) * 16 + col;

    const int ktap = g >> 1;       // score tap for K-half 0 (ktap+2 for half 1)
    const int c0   = (g & 1) * 8;  // this lane's input-channel half

    // A operand (weights), built once: lane holds W'[o=col][kc = g*8+i (+32)].
    // W'[o][k*16+c] = w[(o*KK+k)*C_IN + c].
    bf16x8 w0, w1;
#pragma unroll
    for (int i = 0; i < 8; ++i) {
        w0[i] = f2bf(w[(col * KK + ktap    ) * C_IN + c0 + i]);
        w1[i] = f2bf(w[(col * KK + ktap + 2) * C_IN + c0 + i]);
    }

    const float* xp = in + ((size_t)b * C_IN + c0) * N + n0;  // rows c0..c0+7 via +i*N
    const float* ap = sc + ((size_t)b * KK) * N + n0;
    float*       op = out + (size_t)b * C_OUT * N + (n0 - col);  // tile n-base

    for (int t = 0; t < T_PER_WAVE; ++t) {
        const int off = t * 16;

        // B operand inputs: same x rows serve both K-halves (only the tap differs).
        float xv[8];
#pragma unroll
        for (int i = 0; i < 8; ++i)
            xv[i] = __builtin_nontemporal_load(xp + (size_t)i * N + off);
        const float a0 = __builtin_nontemporal_load(ap + (size_t)ktap       * N + off);
        const float a1 = __builtin_nontemporal_load(ap + (size_t)(ktap + 2) * N + off);

        bf16x8 z0, z1;
#pragma unroll
        for (int i = 0; i < 8; ++i) {
            z0[i] = f2bf(a0 * xv[i]);
            z1[i] = f2bf(a1 * xv[i]);
        }

        f32x4 acc = {0.f, 0.f, 0.f, 0.f};
        acc = __builtin_amdgcn_mfma_f32_16x16x32_bf16(w0, z0, acc, 0, 0, 0);
        acc = __builtin_amdgcn_mfma_f32_16x16x32_bf16(w1, z1, acc, 0, 0, 0);

        // D[row = g*4+r][col] ; row = o.  Write-once stream -> non-temporal.
#pragma unroll
        for (int r = 0; r < 4; ++r)
            __builtin_nontemporal_store(acc[r], op + (size_t)(g * 4 + r) * N + col + off);
    }
}

extern "C" void kernel_launch(void* const* d_in, const int* in_sizes, int n_in,
                              void* d_out, int out_size, void* d_ws, size_t ws_size,
                              hipStream_t stream) {
    const float* in = (const float*)d_in[0];   // (B, C_IN, N)
    const float* w  = (const float*)d_in[1];   // (C_OUT, K, C_IN)
    const float* sc = (const float*)d_in[2];   // (B, K, N)
    float* out = (float*)d_out;                // (B, C_OUT, N)

    TransformConv1d_39264591020709_kernel<<<GRID, 256, 0, stream>>>(in, w, sc, out);
}

// Round 7
// 127.144 us; speedup vs baseline: 1.7765x; 1.7765x over previous
//
#include <hip/hip_runtime.h>
#include <hip/hip_bf16.h>

// out[b,o,n] = sum_{k,c} input[b,c,n] * weight[o,k,c] * score[b,k,n]
// B=8, C_IN=16, C_OUT=16, K=4, N=524288. fp32 in/out.
//
// MFMA formulation: out[b,:,n] = W'(16x64) . Z(64,n),  Z[k*16+c, n] = a[k,n]*x[c,n].
// One wave = one 16(o) x 16(n) tile via 2x mfma_f32_16x16x32_bf16 (K=64).
//
// Round-6 lesson: compiler chose 24 VGPR and serialized the 10 loads/tile ->
// ~3 loads in flight vs ~900cy HBM latency -> latency-bound at 226us with
// every pipe idle. Fix: unroll tiles x4, cluster all 40 loads before compute
// (sched_barrier fence), giving 40-deep MLP per wave.

constexpr int B     = 8;
constexpr int C_IN  = 16;
constexpr int C_OUT = 16;
constexpr int KK    = 4;
constexpr int N     = 524288;                 // 2^19
constexpr int TILES_PER_BATCH = N / 16;       // 32768
constexpr int T_PER_WAVE = 32;                // tiles per wave
constexpr int UN = 4;                         // tiles per load-group
constexpr int TOTAL_WAVES = B * TILES_PER_BATCH / T_PER_WAVE;  // 8192
constexpr int WPB = 4;                        // waves per 256-thread block
constexpr int GRID = TOTAL_WAVES / WPB;       // 2048

typedef short bf16x8 __attribute__((ext_vector_type(8)));
typedef float f32x4  __attribute__((ext_vector_type(4)));

__device__ inline short f2bf(float f) {
    return __builtin_bit_cast(short, __float2bfloat16(f));
}

__global__ __launch_bounds__(256, 4) void
TransformConv1d_39264591020709_kernel(const float* __restrict__ in,
                                      const float* __restrict__ w,
                                      const float* __restrict__ sc,
                                      float* __restrict__ out) {
    const int tid  = threadIdx.x;
    const int lane = tid & 63;
    const int wv   = blockIdx.x * WPB + (tid >> 6);
    const int g    = lane >> 4;    // lane group 0..3
    const int col  = lane & 15;    // n-offset within tile; also o-index for A frag

    const int tile0 = wv * T_PER_WAVE;
    const int b     = tile0 / TILES_PER_BATCH;            // waves never straddle batches
    const int n0    = (tile0 % TILES_PER_BATCH) * 16 + col;

    const int ktap = g >> 1;       // score tap for K-half 0 (ktap+2 for half 1)
    const int c0   = (g & 1) * 8;  // this lane's input-channel half

    // A operand (weights), built once: lane holds W'[o=col][kc = g*8+i (+32)].
    // W'[o][k*16+c] = w[(o*KK+k)*C_IN + c].
    bf16x8 w0, w1;
#pragma unroll
    for (int i = 0; i < 8; ++i) {
        w0[i] = f2bf(w[(col * KK + ktap    ) * C_IN + c0 + i]);
        w1[i] = f2bf(w[(col * KK + ktap + 2) * C_IN + c0 + i]);
    }

    const float* xp = in + ((size_t)b * C_IN + c0) * N + n0;  // rows c0..c0+7 via +i*N
    const float* ap = sc + ((size_t)b * KK) * N + n0;
    float*       op = out + (size_t)b * C_OUT * N + (n0 - col);  // tile n-base

    for (int tt = 0; tt < T_PER_WAVE / UN; ++tt) {
        // ---- load cluster: 40 independent loads, all in flight ----
        float xv[UN][8];
        float a0[UN], a1[UN];
#pragma unroll
        for (int u = 0; u < UN; ++u) {
            const int off = (tt * UN + u) * 16;
#pragma unroll
            for (int i = 0; i < 8; ++i)
                xv[u][i] = xp[(size_t)i * N + off];
            a0[u] = ap[(size_t)ktap       * N + off];
            a1[u] = ap[(size_t)(ktap + 2) * N + off];
        }
        // Keep the load cluster clustered (don't let the scheduler re-serialize
        // loads into the compute to save registers).
        __builtin_amdgcn_sched_barrier(0);

        // ---- compute 4 tiles ----
#pragma unroll
        for (int u = 0; u < UN; ++u) {
            const int off = (tt * UN + u) * 16;
            bf16x8 z0, z1;
#pragma unroll
            for (int i = 0; i < 8; ++i) {
                z0[i] = f2bf(a0[u] * xv[u][i]);
                z1[i] = f2bf(a1[u] * xv[u][i]);
            }
            f32x4 acc = {0.f, 0.f, 0.f, 0.f};
            acc = __builtin_amdgcn_mfma_f32_16x16x32_bf16(w0, z0, acc, 0, 0, 0);
            acc = __builtin_amdgcn_mfma_f32_16x16x32_bf16(w1, z1, acc, 0, 0, 0);

            // D[row = g*4+r][col] ; row = o.  Write-once stream -> non-temporal.
#pragma unroll
            for (int r = 0; r < 4; ++r)
                __builtin_nontemporal_store(acc[r],
                    op + (size_t)(g * 4 + r) * N + col + off);
        }
    }
}

extern "C" void kernel_launch(void* const* d_in, const int* in_sizes, int n_in,
                              void* d_out, int out_size, void* d_ws, size_t ws_size,
                              hipStream_t stream) {
    const float* in = (const float*)d_in[0];   // (B, C_IN, N)
    const float* w  = (const float*)d_in[1];   // (C_OUT, K, C_IN)
    const float* sc = (const float*)d_in[2];   // (B, K, N)
    float* out = (float*)d_out;                // (B, C_OUT, N)

    TransformConv1d_39264591020709_kernel<<<GRID, 256, 0, stream>>>(in, w, sc, out);
}